// Round 13
// baseline (168.446 us; speedup 1.0000x reference)
//
#include <hip/hip_runtime.h>

#define N_NODES 100000
#define N_EDGES 1250000
#define D 64
#define BUCKET_BITS 6                  // 64 nodes / bucket
#define BUCKET_SZ 64
#define NBUCK 1563                     // ceil(100000/64)
#define CAP 1024                       // fixed bucket capacity (mean 800, sigma ~28; max~908)
#define EPT 8                          // edges per thread in bin kernel (max parallelism: 611 blocks)
#define EPB (EPT * 256)                // 2048 edges per block
#define BIN_BLOCKS ((N_EDGES + EPB - 1) / EPB)   // 611
#define TR_BLOCKS ((N_NODES + 63) / 64)          // 1563

// ---------------------------------------------------------------------------
// Workspace layout (bytes):
//   packed  @ 0          : NBUCK*CAP int2 = 12,804,096  (src|dlocal<<20, e)
//   gcursor @ 12,804,096 : NBUCK i32      =      6,252  (zeroed by transform)
//   g16     @ 12,810,368 : N*64 bf16      = 12,800,000  (bf16(h @ W^T))
// total ~= 25.6 MB
// ---------------------------------------------------------------------------

typedef __attribute__((ext_vector_type(8))) short bf16x8;   // MFMA A/B frag (4 VGPR)
typedef __attribute__((ext_vector_type(4))) float f32x4;    // MFMA C/D frag

__device__ __forceinline__ unsigned bf16_rne(float x) {
    unsigned u = __float_as_uint(x);
    return (u + 0x7FFFu + ((u >> 16) & 1u)) >> 16;
}
__device__ __forceinline__ float bf16_to_f(unsigned short v) {
    return __uint_as_float(((unsigned)v) << 16);
}

// Split fp32 -> bf16 hi + bf16 lo with x ~= hi + lo (residual ~2^-18 rel).
__device__ __forceinline__ void bf16_split(float x, short& hi, short& lo) {
    unsigned hb = bf16_rne(x);
    float fh = __uint_as_float(hb << 16);
    hi = (short)hb;
    lo = (short)bf16_rne(x - fh);
}

// g16 = bf16(h @ W^T), MFMA split-bf16, with h staged into LDS via ASYNC
// global_load_lds (width 16). R12 post-mortem: transform was latency-bound
// (VGPR=40 -> 2-4 small loads in flight vs ~900-cyc HBM latency -> 26 us
// at 16% of the ~6 us BW floor). Staging loads bypass VGPRs entirely --
// the compiler cannot sink them (R8 failure mode) and each wave posts
// 4 KB of asynchronous fetch -> HBM-BW-bound. The 16-KB h tile is reused
// for the 8-KB C staging after a barrier. Also zeroes gcursor (safe:
// bin runs in a later dispatch).
__global__ __launch_bounds__(256) void transform_kernel(const float* __restrict__ h,
                                                        const float* __restrict__ W,
                                                        unsigned short* __restrict__ g16,
                                                        int* __restrict__ gcursor) {
    __shared__ __align__(16) char smem[64 * 256];   // 16 KB: h tile, then C-out (8 KB)

    int t = threadIdx.x;
    int bx = blockIdx.x;
    if (bx < 7) {
        int i = bx * 256 + t;
        if (i < NBUCK) gcursor[i] = 0;
    }

    int lane = t & 63;
    int w = t >> 6;
    int li = lane & 15;      // A row / B col within 16-tile
    int lg = lane >> 4;      // k-group (0..3), 8 contiguous k each

    // ---- async-stage this wave's 16 h rows (4 KB) into LDS ----
    // instruction j stages rows [w*16 + j*4, +4): lane i covers row j*4+(i>>4),
    // bytes (i&15)*16. LDS dest = wave-uniform base (+ lane*16 by HW) = linear
    // row-major, exactly matching. Per-lane GLOBAL addr carries the row clamp.
#pragma unroll
    for (int j = 0; j < 4; ++j) {
        int row = bx * 64 + w * 16 + j * 4 + (lane >> 4);
        if (row > N_NODES - 1) row = N_NODES - 1;
        const float* gp = h + (long)row * D + (lane & 15) * 4;
        char* lp = smem + w * 4096 + j * 1024;
        __builtin_amdgcn_global_load_lds((const __attribute__((address_space(1))) void*)gp,
                                         (__attribute__((address_space(3))) void*)lp, 16, 0, 0);
    }
    __syncthreads();   // drains vmcnt(0): all rows staged

    // ---- read A fragments from LDS, split to bf16 hi/lo ----
    const float* myrow = (const float*)(smem + (w * 16 + li) * 256);
    bf16x8 ahi[2], alo[2];
#pragma unroll
    for (int kk = 0; kk < 2; ++kk) {
        float4 h0 = *(const float4*)(myrow + kk * 32 + lg * 8);
        float4 h1 = *(const float4*)(myrow + kk * 32 + lg * 8 + 4);
        float av[8] = {h0.x, h0.y, h0.z, h0.w, h1.x, h1.y, h1.z, h1.w};
        bf16x8 h8, l8;
#pragma unroll
        for (int q = 0; q < 8; ++q) { short a, b; bf16_split(av[q], a, b); h8[q] = a; l8[q] = b; }
        ahi[kk] = h8;
        alo[kk] = l8;
    }
    __syncthreads();   // all waves done reading h tile; smem reusable for C

    // ---- 24 MFMAs: 4 N-tiles x 2 k-steps x 3 split terms (W is L1-hot) ----
    f32x4 acc[4];
#pragma unroll
    for (int nt = 0; nt < 4; ++nt) acc[nt] = (f32x4){0.f, 0.f, 0.f, 0.f};
#pragma unroll
    for (int kk = 0; kk < 2; ++kk) {
#pragma unroll
        for (int nt = 0; nt < 4; ++nt) {
            const float* wp = W + (nt * 16 + li) * D + kk * 32 + lg * 8;
            float4 w0 = *(const float4*)wp;
            float4 w1 = *(const float4*)(wp + 4);
            float bv[8] = {w0.x, w0.y, w0.z, w0.w, w1.x, w1.y, w1.z, w1.w};
            bf16x8 bhi, blo;
#pragma unroll
            for (int q = 0; q < 8; ++q) { short a, b; bf16_split(bv[q], a, b); bhi[q] = a; blo[q] = b; }

            acc[nt] = __builtin_amdgcn_mfma_f32_16x16x32_bf16(ahi[kk], bhi, acc[nt], 0, 0, 0);
            acc[nt] = __builtin_amdgcn_mfma_f32_16x16x32_bf16(ahi[kk], blo, acc[nt], 0, 0, 0);
            acc[nt] = __builtin_amdgcn_mfma_f32_16x16x32_bf16(alo[kk], bhi, acc[nt], 0, 0, 0);
        }
    }

    // C/D layout (m89): col = lane&15, row = (lane>>4)*4 + reg. Stage in LDS.
    unsigned short* sh = (unsigned short*)smem;
#pragma unroll
    for (int nt = 0; nt < 4; ++nt) {
#pragma unroll
        for (int r = 0; r < 4; ++r) {
            sh[(w * 16 + lg * 4 + r) * D + nt * 16 + li] = (unsigned short)bf16_rne(acc[nt][r]);
        }
    }
    __syncthreads();

    // coalesced flush: 512 uint4 per block, 2 per thread.
    const uint4* s4 = (const uint4*)sh;
    uint4* g4 = (uint4*)(g16 + (long)bx * 64 * D);
#pragma unroll
    for (int i = t; i < 512; i += 256) {
        int n = bx * 64 + (i >> 3);
        if (n < N_NODES) g4[i] = s4[i];
    }
}

// Bin edges into fixed-capacity bucket regions: one-pass LDS-ranked design
// at EPT=8 / 611 blocks (max parallelism). One edge-stream read, per-block
// LDS aggregation, one global atomic per nonzero bucket.
__global__ __launch_bounds__(256) void bin_edges_kernel(const int* __restrict__ src,
                                                        const int* __restrict__ dst,
                                                        const float* __restrict__ e,
                                                        int* __restrict__ gcursor,
                                                        int2* __restrict__ packed) {
    __shared__ int lhist[NBUCK];   // counts, then reused as per-block base
    int t = threadIdx.x;
    for (int j = t; j < NBUCK; j += 256) lhist[j] = 0;
    __syncthreads();

    int b[EPT], r[EPT], sv[EPT];
    float ev[EPT];
    int base = blockIdx.x * EPB;
#pragma unroll
    for (int j = 0; j < EPT; ++j) {
        int i = base + j * 256 + t;
        b[j] = -1;
        if (i < N_EDGES) {
            int d = dst[i];
            b[j] = d >> BUCKET_BITS;
            sv[j] = src[i] | ((d & (BUCKET_SZ - 1)) << 20);
            ev[j] = e[i];
            r[j] = atomicAdd(&lhist[b[j]], 1);
        }
    }
    __syncthreads();

    for (int x = t; x < NBUCK; x += 256) {
        int c = lhist[x];
        lhist[x] = (c > 0) ? atomicAdd(&gcursor[x], c) : 0;
    }
    __syncthreads();

#pragma unroll
    for (int j = 0; j < EPT; ++j) {
        if (b[j] >= 0) {
            int pos = lhist[b[j]] + r[j];
            if (pos < CAP) packed[b[j] * CAP + pos] = make_int2(sv[j], __float_as_int(ev[j]));
        }
    }
}

// Per-bucket gather, 512 threads = 8 waves x 8 nodes: counting-sort edges
// by node in LDS (single packed read, register-cached; wave-0 shuffle scan),
// then per-node 8-deep-unrolled register accumulation (R3 lesson: no
// per-edge LDS writes in the hot loop).
__global__ __launch_bounds__(512) void gather_bucket_kernel(const unsigned short* __restrict__ g16,
                                                            const int2* __restrict__ packed,
                                                            const int* __restrict__ gcursor,
                                                            const float* __restrict__ bias,
                                                            float* __restrict__ out) {
    __shared__ int2 eds[CAP];
    __shared__ int nhist[BUCKET_SZ];
    __shared__ int nbase[BUCKET_SZ];
    __shared__ int ncur[BUCKET_SZ];

    int t = threadIdx.x;
    int bk = blockIdx.x;
    int start = bk * CAP;
    int cnt = gcursor[bk];
    if (cnt > CAP) cnt = CAP;

    if (t < BUCKET_SZ) nhist[t] = 0;
    __syncthreads();

    // single packed read, cached in named registers (static indexing)
    int2 pa = make_int2(0, 0), pb = pa;
    bool va = t < cnt, vb = t + 512 < cnt;
    if (va) pa = packed[start + t];
    if (vb) pb = packed[start + t + 512];
    if (va) atomicAdd(&nhist[(pa.x >> 20) & (BUCKET_SZ - 1)], 1);
    if (vb) atomicAdd(&nhist[(pb.x >> 20) & (BUCKET_SZ - 1)], 1);
    __syncthreads();

    // wave-0 shuffle inclusive scan over 64 bins -> exclusive bases
    if (t < BUCKET_SZ) {
        int c = nhist[t];
        int v = c;
#pragma unroll
        for (int off = 1; off < BUCKET_SZ; off <<= 1) {
            int x = __shfl_up(v, off, 64);
            if (t >= off) v += x;
        }
        nbase[t] = v - c;
        ncur[t] = v - c;
    }
    __syncthreads();

    // scatter from registers into node-sorted LDS order
    if (va) { int dl = (pa.x >> 20) & (BUCKET_SZ - 1); eds[atomicAdd(&ncur[dl], 1)] = pa; }
    if (vb) { int dl = (pb.x >> 20) & (BUCKET_SZ - 1); eds[atomicAdd(&ncur[dl], 1)] = pb; }
    __syncthreads();

    // per-node gather: wave w handles nodes [w*8, w*8+8); lane = feature
    int w = t >> 6;
    int lane = t & 63;
    float bv = bias[lane];
    for (int jj = 0; jj < 8; ++jj) {
        int n = w * 8 + jj;
        int gn = bk * BUCKET_SZ + n;
        int s = nbase[n];
        int c = nhist[n];
        float acc = bv;
        int k = 0;
        for (; k + 8 <= c; k += 8) {           // 8 independent 128-B lines in flight
            int2 q0 = eds[s + k + 0], q1 = eds[s + k + 1];
            int2 q2 = eds[s + k + 2], q3 = eds[s + k + 3];
            int2 q4 = eds[s + k + 4], q5 = eds[s + k + 5];
            int2 q6 = eds[s + k + 6], q7 = eds[s + k + 7];
            float g0 = bf16_to_f(g16[(long)(q0.x & 0xFFFFF) * D + lane]);
            float g1 = bf16_to_f(g16[(long)(q1.x & 0xFFFFF) * D + lane]);
            float g2 = bf16_to_f(g16[(long)(q2.x & 0xFFFFF) * D + lane]);
            float g3 = bf16_to_f(g16[(long)(q3.x & 0xFFFFF) * D + lane]);
            float g4 = bf16_to_f(g16[(long)(q4.x & 0xFFFFF) * D + lane]);
            float g5 = bf16_to_f(g16[(long)(q5.x & 0xFFFFF) * D + lane]);
            float g6 = bf16_to_f(g16[(long)(q6.x & 0xFFFFF) * D + lane]);
            float g7 = bf16_to_f(g16[(long)(q7.x & 0xFFFFF) * D + lane]);
            acc += __int_as_float(q0.y) * g0;
            acc += __int_as_float(q1.y) * g1;
            acc += __int_as_float(q2.y) * g2;
            acc += __int_as_float(q3.y) * g3;
            acc += __int_as_float(q4.y) * g4;
            acc += __int_as_float(q5.y) * g5;
            acc += __int_as_float(q6.y) * g6;
            acc += __int_as_float(q7.y) * g7;
        }
        if (k + 4 <= c) {
            int2 q0 = eds[s + k + 0], q1 = eds[s + k + 1];
            int2 q2 = eds[s + k + 2], q3 = eds[s + k + 3];
            float g0 = bf16_to_f(g16[(long)(q0.x & 0xFFFFF) * D + lane]);
            float g1 = bf16_to_f(g16[(long)(q1.x & 0xFFFFF) * D + lane]);
            float g2 = bf16_to_f(g16[(long)(q2.x & 0xFFFFF) * D + lane]);
            float g3 = bf16_to_f(g16[(long)(q3.x & 0xFFFFF) * D + lane]);
            acc += __int_as_float(q0.y) * g0;
            acc += __int_as_float(q1.y) * g1;
            acc += __int_as_float(q2.y) * g2;
            acc += __int_as_float(q3.y) * g3;
            k += 4;
        }
        for (; k < c; ++k) {
            int2 q = eds[s + k];
            acc += __int_as_float(q.y) * bf16_to_f(g16[(long)(q.x & 0xFFFFF) * D + lane]);
        }
        if (gn < N_NODES) out[(long)gn * D + lane] = acc;
    }
}

// ---------------------------------------------------------------------------
extern "C" void kernel_launch(void* const* d_in, const int* in_sizes, int n_in,
                              void* d_out, int out_size, void* d_ws, size_t ws_size,
                              hipStream_t stream) {
    const float* h   = (const float*)d_in[0];
    const float* e   = (const float*)d_in[1];
    const int*   src = (const int*)d_in[2];
    const int*   dst = (const int*)d_in[3];
    const float* W   = (const float*)d_in[4];
    const float* b   = (const float*)d_in[5];
    float* out = (float*)d_out;

    char* ws = (char*)d_ws;
    int2*           packed  = (int2*)          (ws);
    int*            gcursor = (int*)           (ws + 12804096);
    unsigned short* g16     = (unsigned short*)(ws + 12810368);

    // 1) g16 = bf16(h @ W^T), h staged via async global_load_lds (+gcursor zero)
    transform_kernel<<<TR_BLOCKS, 256, 0, stream>>>(h, W, g16, gcursor);

    // 2) one-pass ranked bin, 611 blocks (max parallelism)
    bin_edges_kernel<<<BIN_BLOCKS, 256, 0, stream>>>(src, dst, e, gcursor, packed);

    // 3) per-bucket counting-sort gather + bias (8 waves x 8 nodes, MLP-8)
    gather_bucket_kernel<<<NBUCK, 512, 0, stream>>>(g16, packed, gcursor, b, out);
}

// Round 14
// 163.727 us; speedup vs baseline: 1.0288x; 1.0288x over previous
//
#include <hip/hip_runtime.h>

#define N_NODES 100000
#define N_EDGES 1250000
#define D 64
#define BUCKET_BITS 6                  // 64 nodes / bucket
#define BUCKET_SZ 64
#define NBUCK 1563                     // ceil(100000/64)
#define CAP 1024                       // fixed bucket capacity (mean 800, sigma ~28; max~908)
#define EPT 8                          // edges per thread in bin path (arrays = 32 VGPRs, no spill)
#define EPB (EPT * 256)                // 2048 edges per bin block
#define BIN_BLOCKS ((N_EDGES + EPB - 1) / EPB)   // 611
#define TR_BLOCKS ((N_NODES + 63) / 64)          // 1563
#define FUSED_BLOCKS (TR_BLOCKS + BIN_BLOCKS)    // 2174

// ---------------------------------------------------------------------------
// Workspace layout (bytes):
//   packed  @ 0          : NBUCK*CAP int2 = 12,804,096  (src|dlocal<<20, e)
//   gcursor @ 12,804,096 : NBUCK i32      =      6,252  (hipMemsetAsync zeroed)
//   g16     @ 12,810,368 : N*64 bf16      = 12,800,000  (bf16(h @ W^T))
// total ~= 25.6 MB
//
// R14 = R6 (best measured, 154.9) with ONE counter-evidenced fix: bin path
// EPT 16->8. R6 showed VGPR=60 + WRITE_SIZE 38 MB vs 23 ideal = ~15 MB of
// scratch spill traffic from the bin path's 64-VGPR edge arrays. EPT=8
// halves them to 32 VGPRs (the R2-R4 proven standalone config).
// ---------------------------------------------------------------------------

typedef __attribute__((ext_vector_type(8))) short bf16x8;   // MFMA A/B frag (4 VGPR)
typedef __attribute__((ext_vector_type(4))) float f32x4;    // MFMA C/D frag

__device__ __forceinline__ unsigned bf16_rne(float x) {
    unsigned u = __float_as_uint(x);
    return (u + 0x7FFFu + ((u >> 16) & 1u)) >> 16;
}
__device__ __forceinline__ float bf16_to_f(unsigned short v) {
    return __uint_as_float(((unsigned)v) << 16);
}

// Split fp32 -> bf16 hi + bf16 lo with x ~= hi + lo (residual ~2^-18 rel).
__device__ __forceinline__ void bf16_split(float x, short& hi, short& lo) {
    unsigned hb = bf16_rne(x);
    float fh = __uint_as_float(hb << 16);
    hi = (short)hb;
    lo = (short)bf16_rne(x - fh);
}

// Fused transform + bin, interleaved 2-bin-per-7-blocks (bin density 611/2174).
// Transform = R6's proven single-tile MFMA split-bf16 form. Bin = one-pass
// LDS-ranked (R2-R4 proven) at EPT=8. Shared memory is a union (paths are
// exclusive). Lessons encoded: LDS aggregation only (R7/R10: per-edge global
// atomics and fp32 out-atomics are catastrophic); register-light bin (R6:
// 64-VGPR arrays spill; R8: compiler sinks hoisted loads, don't bother).
__global__ __launch_bounds__(256) void transform_bin_kernel(const float* __restrict__ h,
                                                            const float* __restrict__ W,
                                                            unsigned short* __restrict__ g16,
                                                            const int* __restrict__ src,
                                                            const int* __restrict__ dst,
                                                            const float* __restrict__ e,
                                                            int* __restrict__ gcursor,
                                                            int2* __restrict__ packed) {
    __shared__ __align__(16) char smem_raw[8192];   // union: sh 8192 B | lhist 6252 B

    int t = threadIdx.x;
    int bx = blockIdx.x;
    int g = bx / 7, s = bx % 7;
    int cand = g * 2 + (s - 5);                     // bin id candidate (s>=5 only)
    bool is_bin = (s >= 5) && (cand < BIN_BLOCKS);
    int nb = g * 2 + ((s == 6) ? 1 : 0);            // bin blocks strictly before bx
    if (nb > BIN_BLOCKS) nb = BIN_BLOCKS;

    if (!is_bin) {
        // ================= transform path (R6 proven form) =================
        unsigned short* sh = (unsigned short*)smem_raw;
        int trb = bx - nb;                          // 0..TR_BLOCKS-1 bijective
        int lane = t & 63;
        int w = t >> 6;
        int li = lane & 15;      // A row / B col within 16-tile
        int lg = lane >> 4;      // k-group (0..3), 8 contiguous k each
        int nodebase = trb * 64 + w * 16;

        int arow = nodebase + li;
        if (arow > N_NODES - 1) arow = N_NODES - 1;

        f32x4 acc[4];
#pragma unroll
        for (int nt = 0; nt < 4; ++nt) acc[nt] = (f32x4){0.f, 0.f, 0.f, 0.f};

#pragma unroll
        for (int kk = 0; kk < 2; ++kk) {
            const float* hp = h + (long)arow * D + kk * 32 + lg * 8;
            float4 h0 = *(const float4*)hp;
            float4 h1 = *(const float4*)(hp + 4);
            float av[8] = {h0.x, h0.y, h0.z, h0.w, h1.x, h1.y, h1.z, h1.w};
            bf16x8 ahi, alo;
#pragma unroll
            for (int q = 0; q < 8; ++q) { short a, b; bf16_split(av[q], a, b); ahi[q] = a; alo[q] = b; }

#pragma unroll
            for (int nt = 0; nt < 4; ++nt) {
                const float* wp = W + (nt * 16 + li) * D + kk * 32 + lg * 8;
                float4 w0 = *(const float4*)wp;
                float4 w1 = *(const float4*)(wp + 4);
                float bv[8] = {w0.x, w0.y, w0.z, w0.w, w1.x, w1.y, w1.z, w1.w};
                bf16x8 bhi, blo;
#pragma unroll
                for (int q = 0; q < 8; ++q) { short a, b; bf16_split(bv[q], a, b); bhi[q] = a; blo[q] = b; }

                acc[nt] = __builtin_amdgcn_mfma_f32_16x16x32_bf16(ahi, bhi, acc[nt], 0, 0, 0);
                acc[nt] = __builtin_amdgcn_mfma_f32_16x16x32_bf16(ahi, blo, acc[nt], 0, 0, 0);
                acc[nt] = __builtin_amdgcn_mfma_f32_16x16x32_bf16(alo, bhi, acc[nt], 0, 0, 0);
            }
        }

        // C/D layout (m89): col = lane&15, row = (lane>>4)*4 + reg. Stage in LDS.
#pragma unroll
        for (int nt = 0; nt < 4; ++nt) {
#pragma unroll
            for (int r = 0; r < 4; ++r) {
                sh[(w * 16 + lg * 4 + r) * D + nt * 16 + li] = (unsigned short)bf16_rne(acc[nt][r]);
            }
        }
        __syncthreads();

        // coalesced flush: 512 uint4 per block, 2 per thread.
        const uint4* s4 = (const uint4*)sh;
        uint4* g4 = (uint4*)(g16 + (long)trb * 64 * D);
#pragma unroll
        for (int i = t; i < 512; i += 256) {
            int n = trb * 64 + (i >> 3);
            if (n < N_NODES) g4[i] = s4[i];
        }
    } else {
        // ================= bin path: one-pass ranked, EPT=8 =================
        int* lhist = (int*)smem_raw;                // NBUCK counts -> per-block base
        for (int j = t; j < NBUCK; j += 256) lhist[j] = 0;
        __syncthreads();

        int b[EPT], r[EPT], sv[EPT];
        float ev[EPT];
        int base = cand * EPB;
#pragma unroll
        for (int j = 0; j < EPT; ++j) {
            int i = base + j * 256 + t;
            b[j] = -1;
            if (i < N_EDGES) {
                int d = dst[i];
                b[j] = d >> BUCKET_BITS;
                sv[j] = src[i] | ((d & (BUCKET_SZ - 1)) << 20);
                ev[j] = e[i];
                r[j] = atomicAdd(&lhist[b[j]], 1);
            }
        }
        __syncthreads();

        for (int x = t; x < NBUCK; x += 256) {
            int c = lhist[x];
            lhist[x] = (c > 0) ? atomicAdd(&gcursor[x], c) : 0;
        }
        __syncthreads();

#pragma unroll
        for (int j = 0; j < EPT; ++j) {
            if (b[j] >= 0) {
                int pos = lhist[b[j]] + r[j];
                if (pos < CAP) packed[b[j] * CAP + pos] = make_int2(sv[j], __float_as_int(ev[j]));
            }
        }
    }
}

// Per-bucket gather, 512 threads = 8 waves x 8 nodes: counting-sort edges
// by node in LDS (single packed read, register-cached; wave-0 shuffle scan),
// then per-node 8-deep-unrolled register accumulation (R3 lesson: no
// per-edge LDS writes in the hot loop).
__global__ __launch_bounds__(512) void gather_bucket_kernel(const unsigned short* __restrict__ g16,
                                                            const int2* __restrict__ packed,
                                                            const int* __restrict__ gcursor,
                                                            const float* __restrict__ bias,
                                                            float* __restrict__ out) {
    __shared__ int2 eds[CAP];
    __shared__ int nhist[BUCKET_SZ];
    __shared__ int nbase[BUCKET_SZ];
    __shared__ int ncur[BUCKET_SZ];

    int t = threadIdx.x;
    int bk = blockIdx.x;
    int start = bk * CAP;
    int cnt = gcursor[bk];
    if (cnt > CAP) cnt = CAP;

    if (t < BUCKET_SZ) nhist[t] = 0;
    __syncthreads();

    // single packed read, cached in named registers (static indexing)
    int2 pa = make_int2(0, 0), pb = pa;
    bool va = t < cnt, vb = t + 512 < cnt;
    if (va) pa = packed[start + t];
    if (vb) pb = packed[start + t + 512];
    if (va) atomicAdd(&nhist[(pa.x >> 20) & (BUCKET_SZ - 1)], 1);
    if (vb) atomicAdd(&nhist[(pb.x >> 20) & (BUCKET_SZ - 1)], 1);
    __syncthreads();

    // wave-0 shuffle inclusive scan over 64 bins -> exclusive bases
    if (t < BUCKET_SZ) {
        int c = nhist[t];
        int v = c;
#pragma unroll
        for (int off = 1; off < BUCKET_SZ; off <<= 1) {
            int x = __shfl_up(v, off, 64);
            if (t >= off) v += x;
        }
        nbase[t] = v - c;
        ncur[t] = v - c;
    }
    __syncthreads();

    // scatter from registers into node-sorted LDS order
    if (va) { int dl = (pa.x >> 20) & (BUCKET_SZ - 1); eds[atomicAdd(&ncur[dl], 1)] = pa; }
    if (vb) { int dl = (pb.x >> 20) & (BUCKET_SZ - 1); eds[atomicAdd(&ncur[dl], 1)] = pb; }
    __syncthreads();

    // per-node gather: wave w handles nodes [w*8, w*8+8); lane = feature
    int w = t >> 6;
    int lane = t & 63;
    float bv = bias[lane];
    for (int jj = 0; jj < 8; ++jj) {
        int n = w * 8 + jj;
        int gn = bk * BUCKET_SZ + n;
        int s = nbase[n];
        int c = nhist[n];
        float acc = bv;
        int k = 0;
        for (; k + 8 <= c; k += 8) {           // 8 independent 128-B lines in flight
            int2 q0 = eds[s + k + 0], q1 = eds[s + k + 1];
            int2 q2 = eds[s + k + 2], q3 = eds[s + k + 3];
            int2 q4 = eds[s + k + 4], q5 = eds[s + k + 5];
            int2 q6 = eds[s + k + 6], q7 = eds[s + k + 7];
            float g0 = bf16_to_f(g16[(long)(q0.x & 0xFFFFF) * D + lane]);
            float g1 = bf16_to_f(g16[(long)(q1.x & 0xFFFFF) * D + lane]);
            float g2 = bf16_to_f(g16[(long)(q2.x & 0xFFFFF) * D + lane]);
            float g3 = bf16_to_f(g16[(long)(q3.x & 0xFFFFF) * D + lane]);
            float g4 = bf16_to_f(g16[(long)(q4.x & 0xFFFFF) * D + lane]);
            float g5 = bf16_to_f(g16[(long)(q5.x & 0xFFFFF) * D + lane]);
            float g6 = bf16_to_f(g16[(long)(q6.x & 0xFFFFF) * D + lane]);
            float g7 = bf16_to_f(g16[(long)(q7.x & 0xFFFFF) * D + lane]);
            acc += __int_as_float(q0.y) * g0;
            acc += __int_as_float(q1.y) * g1;
            acc += __int_as_float(q2.y) * g2;
            acc += __int_as_float(q3.y) * g3;
            acc += __int_as_float(q4.y) * g4;
            acc += __int_as_float(q5.y) * g5;
            acc += __int_as_float(q6.y) * g6;
            acc += __int_as_float(q7.y) * g7;
        }
        if (k + 4 <= c) {
            int2 q0 = eds[s + k + 0], q1 = eds[s + k + 1];
            int2 q2 = eds[s + k + 2], q3 = eds[s + k + 3];
            float g0 = bf16_to_f(g16[(long)(q0.x & 0xFFFFF) * D + lane]);
            float g1 = bf16_to_f(g16[(long)(q1.x & 0xFFFFF) * D + lane]);
            float g2 = bf16_to_f(g16[(long)(q2.x & 0xFFFFF) * D + lane]);
            float g3 = bf16_to_f(g16[(long)(q3.x & 0xFFFFF) * D + lane]);
            acc += __int_as_float(q0.y) * g0;
            acc += __int_as_float(q1.y) * g1;
            acc += __int_as_float(q2.y) * g2;
            acc += __int_as_float(q3.y) * g3;
            k += 4;
        }
        for (; k < c; ++k) {
            int2 q = eds[s + k];
            acc += __int_as_float(q.y) * bf16_to_f(g16[(long)(q.x & 0xFFFFF) * D + lane]);
        }
        if (gn < N_NODES) out[(long)gn * D + lane] = acc;
    }
}

// ---------------------------------------------------------------------------
extern "C" void kernel_launch(void* const* d_in, const int* in_sizes, int n_in,
                              void* d_out, int out_size, void* d_ws, size_t ws_size,
                              hipStream_t stream) {
    const float* h   = (const float*)d_in[0];
    const float* e   = (const float*)d_in[1];
    const int*   src = (const int*)d_in[2];
    const int*   dst = (const int*)d_in[3];
    const float* W   = (const float*)d_in[4];
    const float* b   = (const float*)d_in[5];
    float* out = (float*)d_out;

    char* ws = (char*)d_ws;
    int2*           packed  = (int2*)          (ws);
    int*            gcursor = (int*)           (ws + 12804096);
    unsigned short* g16     = (unsigned short*)(ws + 12810368);

    // 1) zero bucket cursors (workspace is poison-filled every iteration)
    hipMemsetAsync(gcursor, 0, NBUCK * sizeof(int), stream);

    // 2) fused transform + bin, interleaved 2:7, spill-free bin path (EPT=8)
    transform_bin_kernel<<<FUSED_BLOCKS, 256, 0, stream>>>(h, W, g16, src, dst, e, gcursor, packed);

    // 3) per-bucket counting-sort gather + bias (8 waves x 8 nodes, MLP-8)
    gather_bucket_kernel<<<NBUCK, 512, 0, stream>>>(g16, packed, gcursor, b, out);
}